// Round 8
// baseline (81.363 us; speedup 1.0000x reference)
//
#include <hip/hip_runtime.h>
#include <math.h>

#define BB 32
#define NN 1024
#define DD 512
#define SS 4
#define RR 64
#define OUTC 256          // SS*RR
#define NT (BB*NN)        // 32768 tokens
#define MT 64             // tokens per fused block
#define NBLK (NT/MT)      // 512
#define BPB (NN/MT)       // blocks per batch = 16

// LDS A-tile geometry: bf16, row stride 44 u16 (88 B): 16-mult? no, but all
// accesses are 8B-aligned b64; bank stride 22 -> <=2-way conflicts (free).
#define ASTR 44
#define APLANE (64*ASTR)       // u16 per plane (hi or lo)
#define ABUF (2*APLANE)        // u16 per chunk buffer (hi+lo)

typedef float4 f4;
typedef float f32x4 __attribute__((ext_vector_type(4)));
typedef __bf16 bf16x8 __attribute__((ext_vector_type(8)));
typedef unsigned short u16x8 __attribute__((ext_vector_type(8)));

union BF8 { u16x8 u; bf16x8 b; unsigned w[4]; };

__device__ __forceinline__ float hif(float f) {
  return __uint_as_float(__float_as_uint(f) & 0xffff0000u);
}
__device__ __forceinline__ unsigned short topu(float f) {
  return (unsigned short)(__float_as_uint(f) >> 16);
}
// identity-order pack: (bf16(e0), bf16(e1)) -> u32 (e0 in low half)
__device__ __forceinline__ unsigned pack2(float e0, float e1) {
  return __builtin_amdgcn_perm(__float_as_uint(e1), __float_as_uint(e0), 0x07060302u);
}

#define MFMA(a,b,c) __builtin_amdgcn_mfma_f32_16x16x32_bf16((a),(b),(c),0,0,0)

// lgkm-only barrier: LDS writes visible across waves; in-flight vmcnt
// register loads survive (no vmcnt drain).
#define BARRIER_LGKM() do { \
  asm volatile("s_waitcnt lgkmcnt(0)" ::: "memory"); \
  __builtin_amdgcn_s_barrier(); \
} while (0)

// ---------------- prep: sub -> bf16 hi/lo; Gram G_s = S_s S_s^T -> bf16 hi/lo
__global__ __launch_bounds__(256) void prep_kernel(const float* __restrict__ sub,
    unsigned short* __restrict__ subhi, unsigned short* __restrict__ sublo,
    unsigned short* __restrict__ Ghi, unsigned short* __restrict__ Glo) {
  int t = threadIdx.x, blk = blockIdx.x;
  __shared__ __align__(16) float Sl[64][36];
  if (blk < 128) {
    int i = (blk*256 + t)*4;                   // 128*256*4 = OUTC*DD
    f4 v = *(const f4*)&sub[i];
    uint2 hh, ll;
    hh.x = pack2(v.x, v.y); hh.y = pack2(v.z, v.w);
    ll.x = pack2(v.x - hif(v.x), v.y - hif(v.y));
    ll.y = pack2(v.z - hif(v.z), v.w - hif(v.w));
    *(uint2*)&subhi[i] = hh;
    *(uint2*)&sublo[i] = ll;
    return;
  }
  int s = blk - 128;
  int lane = t & 63, w = t >> 6, l15 = lane & 15, l4 = lane >> 4;
  int row = t >> 2, seg = t & 3;               // staging: 64 rows x 4 segs of 8
  f4 r0, r1;
  f32x4 acc[4] = {{0,0,0,0},{0,0,0,0},{0,0,0,0},{0,0,0,0}};
  {
    const float* p = &sub[(size_t)(s*RR + row)*DD + seg*8];
    r0 = *(const f4*)p; r1 = *(const f4*)(p+4);
  }
  for (int kc = 0; kc < 16; ++kc) {
    __syncthreads();
    *(f4*)&Sl[row][seg*8]   = r0;
    *(f4*)&Sl[row][seg*8+4] = r1;
    __syncthreads();
    if (kc < 15) {
      const float* p = &sub[(size_t)(s*RR + row)*DD + (kc+1)*32 + seg*8];
      r0 = *(const f4*)p; r1 = *(const f4*)(p+4);
    }
    BF8 ah, al;
    {
      int ra = w*16 + l15;
      f32x4 v0 = *(const f32x4*)&Sl[ra][l4*8];
      f32x4 v1 = *(const f32x4*)&Sl[ra][l4*8+4];
      float ff[8] = {v0[0],v0[1],v0[2],v0[3],v1[0],v1[1],v1[2],v1[3]};
#pragma unroll
      for (int e = 0; e < 8; ++e) { ah.u[e] = topu(ff[e]); al.u[e] = topu(ff[e]-hif(ff[e])); }
    }
#pragma unroll
    for (int j = 0; j < 4; ++j) {
      BF8 bh, bl;
      int rb = j*16 + l15;
      f32x4 v0 = *(const f32x4*)&Sl[rb][l4*8];
      f32x4 v1 = *(const f32x4*)&Sl[rb][l4*8+4];
      float ff[8] = {v0[0],v0[1],v0[2],v0[3],v1[0],v1[1],v1[2],v1[3]};
#pragma unroll
      for (int e = 0; e < 8; ++e) { bh.u[e] = topu(ff[e]); bl.u[e] = topu(ff[e]-hif(ff[e])); }
      acc[j] = MFMA(ah.b, bh.b, acc[j]);
      acc[j] = MFMA(ah.b, bl.b, acc[j]);
      acc[j] = MFMA(al.b, bh.b, acc[j]);
    }
  }
#pragma unroll
  for (int j = 0; j < 4; ++j)
#pragma unroll
    for (int r = 0; r < 4; ++r) {
      int grow = w*16 + l4*4 + r, gcol = j*16 + l15;
      float v = acc[j][r];
      Ghi[((size_t)s*RR + grow)*RR + gcol] = topu(v);
      Glo[((size_t)s*RR + grow)*RR + gcol] = topu(v - hif(v));
    }
}

// ---------------- fused: y = x*sub^T (MFMA), q = y^T G y, sparsemax, partials
// 8 waves (512 thr): wave w -> subspace s=w&3, col-half ch=w>>2.
// Main loop: 8 intervals of 2 k-chunks. Per interval:
//   [loadB x8] -> sched_barrier -> [x reg-loads x2, newest] -> sched_barrier
//   -> kstep x2 -> convert prev x regs -> bf16 hi/lo LDS -> lgkm barrier.
// FIFO-safe: B-waits (vmcnt<=6/<=2) never force the fresh x loads; x loads
// get ~1 interval of latency cover; conversion happens ONCE per element.
__global__ __launch_bounds__(512, 4) void fused_kernel(
    const float* __restrict__ x,
    const unsigned short* __restrict__ subhi, const unsigned short* __restrict__ sublo,
    const unsigned short* __restrict__ Ghi, const unsigned short* __restrict__ Glo,
    float inv_denom, int* __restrict__ amax, float* __restrict__ partial) {
  __shared__ __align__(16) unsigned short ldsA[4*ABUF];  // 45056 B; reused as y scratch
  __shared__ float ssqarr[64][8];
  __shared__ float prq2[64][4][2];
  __shared__ float Wl[64][4];

  int t = threadIdx.x;
  int lane = t & 63, w = t >> 6;
  int s = w & 3, ch = w >> 2;
  int l15 = lane & 15, l4 = lane >> 4;
  int m0 = blockIdx.x * MT;

  int srow = t >> 3, sseg = t & 7;             // staging: 64 rows x 8 segs of 4 floats
  const float* xrow = &x[(size_t)(m0 + srow)*DD + sseg*4];

  f32x4 acc[4][2] = {};
  float ssqp = 0.f;

  auto gload = [&](int c) -> f4 {
    return *(const f4*)(xrow + c*32);
  };
  auto cvtwrite = [&](int buf, f4 v) {
    float f0=v.x, f1=v.y, f2=v.z, f3=v.w;
    ssqp += f0*f0 + f1*f1 + f2*f2 + f3*f3;
    uint2 hh, ll;
    hh.x = pack2(f0,f1); hh.y = pack2(f2,f3);
    ll.x = pack2(f0-hif(f0), f1-hif(f1));
    ll.y = pack2(f2-hif(f2), f3-hif(f3));
    unsigned short* p = &ldsA[buf*ABUF + srow*ASTR + sseg*4];
    *(uint2*)p = hh;                 // hi plane
    *(uint2*)(p + APLANE) = ll;      // lo plane
  };
  auto loadB = [&](BF8 (&bh)[2], BF8 (&bl)[2], int c) {
#pragma unroll
    for (int nf = 0; nf < 2; ++nf) {
      size_t off = (size_t)(s*64 + ch*32 + nf*16 + l15)*DD + c*32 + l4*8;
      bh[nf].u = *(const u16x8*)&subhi[off];
      bl[nf].u = *(const u16x8*)&sublo[off];
    }
  };
  auto kstep = [&](int buf, BF8 (&bh)[2], BF8 (&bl)[2]) {
#pragma unroll
    for (int mf = 0; mf < 4; ++mf) {
      int row = mf*16 + l15;
      const unsigned short* p = &ldsA[buf*ABUF + row*ASTR + l4*8];
      uint2 h0  = *(const uint2*)p;
      uint2 h1  = *(const uint2*)(p + 4);
      uint2 lo0 = *(const uint2*)(p + APLANE);
      uint2 lo1 = *(const uint2*)(p + APLANE + 4);
      BF8 ah, al;
      ah.w[0]=h0.x;  ah.w[1]=h0.y;  ah.w[2]=h1.x;  ah.w[3]=h1.y;
      al.w[0]=lo0.x; al.w[1]=lo0.y; al.w[2]=lo1.x; al.w[3]=lo1.y;
#pragma unroll
      for (int nf = 0; nf < 2; ++nf) {
        acc[mf][nf] = MFMA(ah.b, bh[nf].b, acc[mf][nf]);
        acc[mf][nf] = MFMA(ah.b, bl[nf].b, acc[mf][nf]);
        acc[mf][nf] = MFMA(al.b, bh[nf].b, acc[mf][nf]);
      }
    }
  };

  // prologue: chunks 0,1 convert+write; chunks 2,3 into xrB regs
  f4 xrA0 = gload(0), xrA1 = gload(1);
  cvtwrite(0, xrA0); cvtwrite(1, xrA1);
  f4 xrB0 = gload(2), xrB1 = gload(3);
  BARRIER_LGKM();

#pragma unroll
  for (int i = 0; i < 8; ++i) {
    const int cons = (i & 1) * 2;        // buffers consumed this interval
    const int wr   = cons ^ 2;           // buffers written this interval
    BF8 bhA[2], blA[2], bhB[2], blB[2];
    loadB(bhA, blA, 2*i);
    loadB(bhB, blB, 2*i + 1);
    __builtin_amdgcn_sched_barrier(0);   // pin: B loads issue first
    if (i < 6) {
      if ((i & 1) == 0) { xrA0 = gload(2*i + 4); xrA1 = gload(2*i + 5); }
      else              { xrB0 = gload(2*i + 4); xrB1 = gload(2*i + 5); }
    }
    __builtin_amdgcn_sched_barrier(0);   // pin: x loads newest before compute
    kstep(cons,     bhA, blA);
    kstep(cons + 1, bhB, blB);
    if (i < 7) {
      if ((i & 1) == 0) { cvtwrite(wr, xrB0); cvtwrite(wr + 1, xrB1); }
      else              { cvtwrite(wr, xrA0); cvtwrite(wr + 1, xrA1); }
    }
    BARRIER_LGKM();
  }
  ssqarr[srow][sseg] = ssqp;

  // G fragments (L2-resident); identity-order elements match Ghi scalar layout
  BF8 gh[2][2], gl2[2][2];
#pragma unroll
  for (int kf = 0; kf < 2; ++kf)
#pragma unroll
    for (int nf = 0; nf < 2; ++nf) {
      size_t off = (size_t)(s*RR + (ch*2 + nf)*16 + l15)*RR + kf*32 + l4*8;
      gh[kf][nf].u  = *(const u16x8*)&Ghi[off];
      gl2[kf][nf].u = *(const u16x8*)&Glo[off];
    }
  __syncthreads();   // full drain; stage area becomes y scratch

  float* ysc = (float*)&ldsA[0];       // [s][16][68] f32 = 17408 B <= 45056
#pragma unroll
  for (int h = 0; h < 4; ++h) {
#pragma unroll
    for (int nf = 0; nf < 2; ++nf)
#pragma unroll
      for (int r = 0; r < 4; ++r)
        ysc[s*1088 + (l4*4 + r)*68 + ch*32 + nf*16 + l15] = acc[h][nf][r];
    __syncthreads();                // ysc[s] complete (both halves)
    BF8 yh[2], yl[2];
#pragma unroll
    for (int kf = 0; kf < 2; ++kf) {
      int base = s*1088 + l15*68 + kf*32 + l4*8;
      f32x4 v0 = *(const f32x4*)&ysc[base];
      f32x4 v1 = *(const f32x4*)&ysc[base+4];
      float ff[8] = {v0[0],v0[1],v0[2],v0[3],v1[0],v1[1],v1[2],v1[3]};
#pragma unroll
      for (int e = 0; e < 8; ++e) {
        yh[kf].u[e] = topu(ff[e]);
        yl[kf].u[e] = topu(ff[e] - hif(ff[e]));
      }
    }
    f32x4 z[2] = {};
#pragma unroll
    for (int nf = 0; nf < 2; ++nf)
#pragma unroll
      for (int kf = 0; kf < 2; ++kf) {
        z[nf] = MFMA(yh[kf].b, gh[kf][nf].b,  z[nf]);
        z[nf] = MFMA(yh[kf].b, gl2[kf][nf].b, z[nf]);
        z[nf] = MFMA(yl[kf].b, gh[kf][nf].b,  z[nf]);
      }
#pragma unroll
    for (int r = 0; r < 4; ++r) {
      float qp = z[0][r]*acc[h][0][r] + z[1][r]*acc[h][1][r];
      qp += __shfl_xor(qp, 1); qp += __shfl_xor(qp, 2);
      qp += __shfl_xor(qp, 4); qp += __shfl_xor(qp, 8);
      if (l15 == 0) prq2[h*16 + l4*4 + r][s][ch] = qp;
    }
    __syncthreads();                // readers done before next h overwrites
  }

  if (t < MT) {
    float ss = 0.f;
#pragma unroll
    for (int g = 0; g < 8; ++g) ss += ssqarr[t][g];
    float inv = 1.f / fmaxf(sqrtf(ss), 1e-12f);
    float p0 = sqrtf(fmaxf(prq2[t][0][0] + prq2[t][0][1], 0.f)) * inv * inv_denom;
    float p1 = sqrtf(fmaxf(prq2[t][1][0] + prq2[t][1][1], 0.f)) * inv * inv_denom;
    float p2 = sqrtf(fmaxf(prq2[t][2][0] + prq2[t][2][1], 0.f)) * inv * inv_denom;
    float p3 = sqrtf(fmaxf(prq2[t][3][0] + prq2[t][3][1], 0.f)) * inv * inv_denom;
    float a0=p0, a1=p1, a2=p2, a3=p3, hi, lo;
    hi = fmaxf(a0,a1); lo = fminf(a0,a1); a0=hi; a1=lo;
    hi = fmaxf(a2,a3); lo = fminf(a2,a3); a2=hi; a3=lo;
    hi = fmaxf(a0,a2); lo = fminf(a0,a2); a0=hi; a2=lo;
    hi = fmaxf(a1,a3); lo = fminf(a1,a3); a1=hi; a3=lo;
    hi = fmaxf(a1,a2); lo = fminf(a1,a2); a1=hi; a2=lo;
    float c2 = a0+a1, c3 = c2+a2, c4s = c3+a3;
    int ksup = 1 + (2.f*a1 > c2-1.f) + (3.f*a2 > c3-1.f) + (4.f*a3 > c4s-1.f);
    float csel = (ksup==1) ? a0 : (ksup==2) ? c2 : (ksup==3) ? c3 : c4s;
    float tau = (csel - 1.f) / (float)ksup;
    float q0 = fmaxf(p0-tau, 0.f), q1 = fmaxf(p1-tau, 0.f);
    float q2 = fmaxf(p2-tau, 0.f), q3 = fmaxf(p3-tau, 0.f);
    int arg = 0; float best = q0;
    if (q1 > best) { best = q1; arg = 1; }
    if (q2 > best) { best = q2; arg = 2; }
    if (q3 > best) { best = q3; arg = 3; }
    amax[m0 + t] = arg;
    Wl[t][0] = q0*inv; Wl[t][1] = q1*inv; Wl[t][2] = q2*inv; Wl[t][3] = q3*inv;
  }
  __syncthreads();

  // per-subspace feature partials over this block's 64 tokens (x re-read ~L2)
  {
    int grp = t >> 7, dcol = t & 127;      // grp = subspace, 128 dcols of f32x4
    f32x4 a0 = {0,0,0,0};
#pragma unroll 8
    for (int tok = 0; tok < MT; ++tok) {
      f32x4 v = *(const f32x4*)&x[(size_t)(m0 + tok)*DD + dcol*4];
      a0 += v * Wl[tok][grp];
    }
    *(f32x4*)&partial[((size_t)blockIdx.x*4 + grp)*DD + dcol*4] = a0;
  }
}

// ---------------- finish: majority vote + select/reduce partials -----------
__global__ __launch_bounds__(256) void finish_kernel(const int* __restrict__ amax,
    const float* __restrict__ partial, const int* __restrict__ mask,
    float* __restrict__ out) {
  __shared__ int cnt[4];
  __shared__ int vsh;
  int bb = blockIdx.x, t = threadIdx.x;
  if (t < 4) cnt[t] = 0;
  __syncthreads();
  int m = mask[bb];
  int c0=0, c1=0, c2=0, c3=0;
  for (int n = t; n < NN; n += 256) {
    if (n < m) {
      int a = amax[bb*NN + n];
      c0 += (a==0); c1 += (a==1); c2 += (a==2); c3 += (a==3);
    }
  }
  atomicAdd(&cnt[0], c0); atomicAdd(&cnt[1], c1);
  atomicAdd(&cnt[2], c2); atomicAdd(&cnt[3], c3);
  __syncthreads();
  if (t == 0) {
    int arg = 0, best = cnt[0];
    if (cnt[1] > best) { best = cnt[1]; arg = 1; }
    if (cnt[2] > best) { best = cnt[2]; arg = 2; }
    if (cnt[3] > best) { best = cnt[3]; arg = 3; }
    vsh = arg;
  }
  __syncthreads();
  int v = vsh;
  for (int d = t; d < DD; d += 256) {
    float f = 0.f;
#pragma unroll
    for (int c = 0; c < BPB; ++c)
      f += partial[(((size_t)(bb*BPB + c))*4 + v)*DD + d];
    out[bb*DD + d] = f;
  }
}

extern "C" void kernel_launch(void* const* d_in, const int* in_sizes, int n_in,
                              void* d_out, int out_size, void* d_ws, size_t ws_size,
                              hipStream_t stream) {
  const float* x    = (const float*)d_in[0];
  const int*   mask = (const int*)d_in[1];
  const float* sub  = (const float*)d_in[2];
  float* out = (float*)d_out;

  float* partial = (float*)d_ws;                         // 512*4*512 f32 = 4 MB
  int*   amax    = (int*)(partial + (size_t)NBLK*4*DD);  // 32768 ints
  unsigned short* subhi = (unsigned short*)(amax + NT);  // 131072 u16
  unsigned short* sublo = subhi + OUTC*DD;
  unsigned short* Ghi   = sublo + OUTC*DD;               // 16384 u16
  unsigned short* Glo   = Ghi + SS*RR*RR;

  // SCALE = 1.718*exp(-count/30000) - 0.718, count = B = 32
  double scale = 1.718 * exp(-((double)BB) / 30000.0) - 0.718;
  float inv_denom = (float)(1.0 / ((double)DD * scale));

  prep_kernel<<<128 + SS, 256, 0, stream>>>(sub, subhi, sublo, Ghi, Glo);
  fused_kernel<<<NBLK, 512, 0, stream>>>(x, subhi, sublo, Ghi, Glo, inv_denom, amax, partial);
  finish_kernel<<<BB, 256, 0, stream>>>(amax, partial, mask, out);
}